// Round 8
// baseline (688.060 us; speedup 1.0000x reference)
//
#include <hip/hip_runtime.h>
#include <hip/hip_bf16.h>
#include <cmath>
#include <cstdint>

typedef __bf16 bf16_t;
typedef bf16_t bf16x8 __attribute__((ext_vector_type(8)));
typedef float  f32x4  __attribute__((ext_vector_type(4)));
typedef int    i32x4  __attribute__((ext_vector_type(4)));
typedef int    i32x8  __attribute__((ext_vector_type(8)));

#define VOCAB 32000
#define DDIM  1024
#define BATCH 4
#define SEQ   2048
#define MTOT  (BATCH*SEQ)                       // 8192
#define LOGITS_ELEMS (262144000LL)              // MTOT*VOCAB

// ---- ws layout (bytes) ----
#define WQKV_OFF 0LL                            // Wqkv8 fp8 [3072][1024] (3MB)
#define WOUT_OFF 6291456LL                      // Wout8 fp8 [32000][1024] (32MB)
#define AO8_OFF  (WOUT_OFF + 33554432LL)        // Ao8 fp8 [8192][1024] (8MB)
#define X8_OFF   71827456LL                     // X8 fp8 [8192][1024] (8MB)
#define QKV8_OFF 88604672LL                     // QKV8 fp8 [8192][3072] (24MB)
#define VT_OFF   138936320LL                    // Vt8 fp8 [4][1024][2048] (8MB)
#define ABF_OFF  155713536LL                    // scores bf16 [4][2048][2048]; A8 fp8 in place
// END = 189267968 bytes required in ws

#define SC127 0x7F7F7F7F                        // E8M0 identity scales (2^0)

__device__ __forceinline__ void gl_lds16(const void* g, void* l) {
  __builtin_amdgcn_global_load_lds(
      (const __attribute__((address_space(1))) void*)g,
      (__attribute__((address_space(3))) void*)l, 16, 0, 0);
}

__device__ __forceinline__ i32x8 join8(i32x4 lo, i32x4 hi) {
  i32x8 r;
  r[0] = lo[0]; r[1] = lo[1]; r[2] = lo[2]; r[3] = lo[3];
  r[4] = hi[0]; r[5] = hi[1]; r[6] = hi[2]; r[7] = hi[3];
  return r;
}

__device__ __forceinline__ unsigned char to_fp8(float v) {
  int p = __builtin_amdgcn_cvt_pk_fp8_f32(v, v, 0, false);
  return (unsigned char)(p & 0xFF);
}

// ---------------- f32 -> fp8(e4m3) quant, software pow-2 scale ----------------
__global__ __launch_bounds__(256)
void quant_fp8_f32(const float* __restrict__ s, int2* __restrict__ d, int n8, float scale) {
  int i = blockIdx.x * 256 + threadIdx.x;
  const int stride = gridDim.x * 256;
  for (; i < n8; i += stride) {
    float4 a = ((const float4*)s)[i * 2];
    float4 b = ((const float4*)s)[i * 2 + 1];
    int lo = 0, hi = 0;
    lo = __builtin_amdgcn_cvt_pk_fp8_f32(a.x * scale, a.y * scale, lo, false);
    lo = __builtin_amdgcn_cvt_pk_fp8_f32(a.z * scale, a.w * scale, lo, true);
    hi = __builtin_amdgcn_cvt_pk_fp8_f32(b.x * scale, b.y * scale, hi, false);
    hi = __builtin_amdgcn_cvt_pk_fp8_f32(b.z * scale, b.w * scale, hi, true);
    d[i] = make_int2(lo, hi);
  }
}

// ---------------- embedding gather + fp8 quant (x64) ----------------
__global__ __launch_bounds__(256)
void gather_fp8(const int* __restrict__ idx, const float* __restrict__ embed,
                unsigned char* __restrict__ X8) {
  const int m = blockIdx.x;
  const int row = idx[m];
  float4 v = ((const float4*)(embed + (long long)row * DDIM))[threadIdx.x];
  int p = 0;
  p = __builtin_amdgcn_cvt_pk_fp8_f32(v.x * 64.f, v.y * 64.f, p, false);
  p = __builtin_amdgcn_cvt_pk_fp8_f32(v.z * 64.f, v.w * 64.f, p, true);
  ((int*)(X8 + (long long)m * DDIM))[threadIdx.x] = p;
}

// ---------------- V transpose (bytes): QKV8 cols[2048..3071] -> Vt8[b][d][s] ----------------
__global__ __launch_bounds__(256)
void transpose_v8(const unsigned char* __restrict__ QKV8, unsigned char* __restrict__ Vt8) {
  __shared__ unsigned char tile[64][68];
  const int b = blockIdx.z;
  const int s0 = blockIdx.x * 64, d0 = blockIdx.y * 64;
  const int tx = threadIdx.x & 63, ty = threadIdx.x >> 6;
  #pragma unroll
  for (int i = ty; i < 64; i += 4)
    tile[i][tx] = QKV8[((long long)(b * SEQ + s0 + i)) * 3072 + 2048 + d0 + tx];
  __syncthreads();
  #pragma unroll
  for (int i = ty; i < 64; i += 4)
    Vt8[((long long)(b * DDIM + d0 + i)) * SEQ + s0 + tx] = tile[tx][i];
}

// ---------------- 128x128 fp8 BT-GEMM, single-buffer (scores / PV) ----------------
// OMODE: 0 = fp8 out (v*rescale), 3 = bf16 out (v*rescale).
template<int OMODE, bool CSKIP, bool CTRIM>
__global__ __launch_bounds__(256)
void gemm_bt_fp8(const unsigned char* __restrict__ A, const unsigned char* __restrict__ B,
                 void* __restrict__ Cv, int K, int lda, int ldb, int ldc,
                 long long sA, long long sB, long long sC, float rescale) {
  const int bn = blockIdx.x, bm = blockIdx.y, bz = blockIdx.z;
  if (CSKIP && bn > bm) return;

  __shared__ unsigned char As8[128 * 128];
  __shared__ unsigned char Bs8[128 * 128];

  const int t = threadIdx.x;
  const int lane = t & 63;
  const int w = t >> 6;
  const int wr = w >> 1, wc = w & 1;
  const int fr = lane & 15, fq = lane >> 4;

  f32x4 acc[4][4];
  #pragma unroll
  for (int m = 0; m < 4; m++)
    #pragma unroll
    for (int n = 0; n < 4; n++)
      #pragma unroll
      for (int r = 0; r < 4; r++) acc[m][n][r] = 0.f;

  int kEnd = K;
  if (CTRIM) { int ke = (bm + 1) * 128; kEnd = ke < K ? ke : K; }

  const unsigned char* Ab = A + bz * sA + (long long)(bm * 128) * lda;
  const unsigned char* Bb = B + bz * sB + (long long)(bn * 128) * ldb;

  const int srow = t >> 3;                       // 0..31
  const int gsw = ((t & 7) ^ (srow & 7)) * 16;   // pre-swizzled source granule

  int offA8[4][2], offB8[4][2];
  #pragma unroll
  for (int m = 0; m < 4; ++m)
    #pragma unroll
    for (int h = 0; h < 2; ++h) {
      const int r = wr * 64 + m * 16 + fr;
      offA8[m][h] = r * 128 + (((2 * fq + h) ^ (r & 7)) * 16);
    }
  #pragma unroll
  for (int n = 0; n < 4; ++n)
    #pragma unroll
    for (int h = 0; h < 2; ++h) {
      const int r = wc * 64 + n * 16 + fr;
      offB8[n][h] = r * 128 + (((2 * fq + h) ^ (r & 7)) * 16);
    }

  for (int k0 = 0; k0 < kEnd; k0 += 128) {
    #pragma unroll
    for (int p = 0; p < 4; ++p) {
      gl_lds16(Ab + (long long)(p * 32 + srow) * lda + k0 + gsw, &As8[p * 4096 + t * 16]);
      gl_lds16(Bb + (long long)(p * 32 + srow) * ldb + k0 + gsw, &Bs8[p * 4096 + t * 16]);
    }
    __syncthreads();

    i32x8 af8[4], bv8[4];
    #pragma unroll
    for (int m = 0; m < 4; ++m)
      af8[m] = join8(*(const i32x4*)&As8[offA8[m][0]], *(const i32x4*)&As8[offA8[m][1]]);
    #pragma unroll
    for (int n = 0; n < 4; ++n)
      bv8[n] = join8(*(const i32x4*)&Bs8[offB8[n][0]], *(const i32x4*)&Bs8[offB8[n][1]]);
    #pragma unroll
    for (int m = 0; m < 4; ++m)
      #pragma unroll
      for (int n = 0; n < 4; ++n)
        acc[m][n] = __builtin_amdgcn_mfma_scale_f32_16x16x128_f8f6f4(
            af8[m], bv8[n], acc[m][n], 0, 0, 0, SC127, 0, SC127);
    __syncthreads();
  }

  const int row0 = bm * 128 + wr * 64 + fq * 4;
  const int col0 = bn * 128 + wc * 64 + fr;
  #pragma unroll
  for (int m = 0; m < 4; m++)
    #pragma unroll
    for (int n = 0; n < 4; n++) {
      const int col = col0 + n * 16;
      #pragma unroll
      for (int r = 0; r < 4; r++) {
        const int row = row0 + m * 16 + r;
        const float v = acc[m][n][r] * rescale;
        if (OMODE == 0)
          ((unsigned char*)Cv)[bz * sC + (long long)row * ldc + col] = to_fp8(v);
        else
          ((bf16_t*)Cv)[bz * sC + (long long)row * ldc + col] = (bf16_t)v;
      }
    }
}

// ---------------- 128x128 fp8 BT-GEMM, double-buffered 2-phase (logits) ----------------
// 64 KB LDS -> 2-3 blocks/CU: cross-block TLP overlaps epilogue f32 writes and
// stage stalls with other blocks' MFMA (m114 implicit overlap). Schedule per
// K-tile: STAGE(next) first, ds_read(cur), lgkmcnt(0), MFMA, vmcnt(0), barrier.
// f32 out + bias. Grid (bn=250, bm=64): x-fastest dispatch partitions B into
// per-XCD L2-resident 4MB slices; A is L3-resident.
__global__ __launch_bounds__(256)
void gemm128_fp8_dbuf(const unsigned char* __restrict__ A, const unsigned char* __restrict__ B,
                      float* __restrict__ Cv, const float* __restrict__ bias,
                      int K, int lda, int ldb, int ldc, float rescale) {
  __shared__ unsigned char As8[2][128 * 128];
  __shared__ unsigned char Bs8[2][128 * 128];

  const int bn = blockIdx.x, bm = blockIdx.y;
  const int t = threadIdx.x;
  const int lane = t & 63;
  const int w = t >> 6;
  const int wr = w >> 1, wc = w & 1;
  const int fr = lane & 15, fq = lane >> 4;

  f32x4 acc[4][4];
  #pragma unroll
  for (int m = 0; m < 4; m++)
    #pragma unroll
    for (int n = 0; n < 4; n++)
      #pragma unroll
      for (int r = 0; r < 4; r++) acc[m][n][r] = 0.f;

  const unsigned char* Ab = A + (long long)(bm * 128) * lda;
  const unsigned char* Bb = B + (long long)(bn * 128) * ldb;

  const int srow = t >> 3;
  const int gsw = ((t & 7) ^ (srow & 7)) * 16;

  int offA8[4][2], offB8[4][2];
  #pragma unroll
  for (int m = 0; m < 4; ++m)
    #pragma unroll
    for (int h = 0; h < 2; ++h) {
      const int r = wr * 64 + m * 16 + fr;
      offA8[m][h] = r * 128 + (((2 * fq + h) ^ (r & 7)) * 16);
    }
  #pragma unroll
  for (int n = 0; n < 4; ++n)
    #pragma unroll
    for (int h = 0; h < 2; ++h) {
      const int r = wc * 64 + n * 16 + fr;
      offB8[n][h] = r * 128 + (((2 * fq + h) ^ (r & 7)) * 16);
    }

#define STG128(buf, k0) do {                                                   \
    _Pragma("unroll")                                                          \
    for (int p_ = 0; p_ < 4; ++p_) {                                           \
      gl_lds16(Ab + (long long)(p_ * 32 + srow) * lda + (k0) + gsw,            \
               &As8[buf][p_ * 4096 + t * 16]);                                 \
      gl_lds16(Bb + (long long)(p_ * 32 + srow) * ldb + (k0) + gsw,            \
               &Bs8[buf][p_ * 4096 + t * 16]);                                 \
    }                                                                          \
  } while (0)

  const int NT = K >> 7;
  STG128(0, 0);
  asm volatile("s_waitcnt vmcnt(0)" ::: "memory");
  __builtin_amdgcn_s_barrier();

  int b = 0;
  for (int t8 = 0; t8 < NT; ++t8, b ^= 1) {
    if (t8 + 1 < NT) STG128(b ^ 1, (t8 + 1) << 7);   // loads in flight across MFMA

    i32x8 af8[4], bv8[4];
    #pragma unroll
    for (int m = 0; m < 4; ++m)
      af8[m] = join8(*(const i32x4*)&As8[b][offA8[m][0]], *(const i32x4*)&As8[b][offA8[m][1]]);
    #pragma unroll
    for (int n = 0; n < 4; ++n)
      bv8[n] = join8(*(const i32x4*)&Bs8[b][offB8[n][0]], *(const i32x4*)&Bs8[b][offB8[n][1]]);
    asm volatile("s_waitcnt lgkmcnt(0)" ::: "memory");
    __builtin_amdgcn_sched_barrier(0);
    __builtin_amdgcn_s_setprio(1);
    #pragma unroll
    for (int m = 0; m < 4; ++m)
      #pragma unroll
      for (int n = 0; n < 4; ++n)
        acc[m][n] = __builtin_amdgcn_mfma_scale_f32_16x16x128_f8f6f4(
            af8[m], bv8[n], acc[m][n], 0, 0, 0, SC127, 0, SC127);
    __builtin_amdgcn_s_setprio(0);
    asm volatile("" ::: "memory");
    if (t8 + 1 < NT) asm volatile("s_waitcnt vmcnt(0)" ::: "memory");
    __builtin_amdgcn_s_barrier();
  }
#undef STG128

  const int row0 = bm * 128 + wr * 64 + fq * 4;
  const int col0 = bn * 128 + wc * 64 + fr;
  #pragma unroll
  for (int m = 0; m < 4; m++)
    #pragma unroll
    for (int n = 0; n < 4; n++) {
      const int col = col0 + n * 16;
      const float bb = bias[col];
      #pragma unroll
      for (int r = 0; r < 4; r++)
        Cv[(long long)(row0 + m * 16 + r) * ldc + col] = acc[m][n][r] * rescale + bb;
    }
}

// ---------------- shared phase-sync macros (256² 8-phase) ----------------
#define PHASE_MID() do {                                                  \
    asm volatile("" ::: "memory");                                        \
    __builtin_amdgcn_s_barrier();                                         \
    asm volatile("s_waitcnt lgkmcnt(0)" ::: "memory");                    \
    __builtin_amdgcn_sched_barrier(0);                                    \
    __builtin_amdgcn_s_setprio(1);                                        \
  } while (0)

#define PHASE_END() do {                                                  \
    __builtin_amdgcn_s_setprio(0);                                        \
    asm volatile("" ::: "memory");                                        \
    __builtin_amdgcn_s_barrier();                                         \
  } while (0)

// ---------------- 256x256 8-phase MX-fp8 BT-GEMM (QKV) ----------------
#define STAGE8(buf, h, src, ld, k0) do {                                  \
    gl_lds16((src) + (k0), &lds8[buf][h][tt * 16]);                       \
    gl_lds16((src) + (long long)64 * (ld) + (k0), &lds8[buf][h][8192 + tt * 16]); \
  } while (0)

#define LDA_FRAGS8(buf, qm)                                               \
  _Pragma("unroll") for (int m_ = 0; m_ < 4; ++m_) {                      \
    i32x4 lo_ = *(const i32x4*)&lds8[buf][qm][offA8[m_][0]];              \
    i32x4 hi_ = *(const i32x4*)&lds8[buf][qm][offA8[m_][1]];              \
    af8[m_] = join8(lo_, hi_);                                            \
  }

#define LDB_FRAGS8(buf, qn)                                               \
  _Pragma("unroll") for (int n_ = 0; n_ < 2; ++n_) {                      \
    i32x4 lo_ = *(const i32x4*)&lds8[buf][2 + (qn)][offB8[n_][0]];        \
    i32x4 hi_ = *(const i32x4*)&lds8[buf][2 + (qn)][offB8[n_][1]];        \
    bv8[qn][n_] = join8(lo_, hi_);                                        \
  }

#define MFMA_Q8(qm, qn)                                                   \
  _Pragma("unroll") for (int m_ = 0; m_ < 4; ++m_)                        \
  _Pragma("unroll") for (int n_ = 0; n_ < 2; ++n_)                        \
    acc[qm][qn][m_][n_] = __builtin_amdgcn_mfma_scale_f32_16x16x128_f8f6f4( \
        af8[m_], bv8[qn][n_], acc[qm][qn][m_][n_], 0, 0, 0, SC127, 0, SC127);

template<int OMODE>   // 0: fp8 out (v*rescale); 2: f32 out + bias
__global__ __launch_bounds__(512, 2)
void gemm256_fp8(const unsigned char* __restrict__ A, const unsigned char* __restrict__ B,
                 void* __restrict__ Cv, const float* __restrict__ bias,
                 int K, int lda, int ldb, int ldc, int nbn, float rescale) {
  __shared__ unsigned char lds8[2][4][16384];

  const int nwg = gridDim.x;
  const int bid = blockIdx.x;
  const int swz = (nwg & 7) ? bid : ((bid & 7) * (nwg >> 3) + (bid >> 3));
  const int per_group = 8 * nbn;
  const int g   = swz / per_group;
  const int rem = swz - g * per_group;
  const int bm = g * 8 + (rem & 7);
  const int bn = rem >> 3;

  const int tt = threadIdx.x;
  const int lane = tt & 63;
  const int w = tt >> 6;
  const int wr = w >> 2, wc = w & 3;
  const int fr = lane & 15, fq = lane >> 4;

  const int srow = tt >> 3;
  const int gl = (tt & 7) ^ (srow & 7);
  const unsigned char* sA0 = A + (long long)(bm * 256 +       srow) * lda + gl * 16;
  const unsigned char* sA1 = A + (long long)(bm * 256 + 128 + srow) * lda + gl * 16;
  const unsigned char* sB0 = B + (long long)(bn * 256 +       srow) * ldb + gl * 16;
  const unsigned char* sB1 = B + (long long)(bn * 256 + 128 + srow) * ldb + gl * 16;

  int offA8[4][2], offB8[2][2];
  #pragma unroll
  for (int m = 0; m < 4; ++m)
    #pragma unroll
    for (int h = 0; h < 2; ++h) {
      const int r = wr * 64 + m * 16 + fr;
      offA8[m][h] = r * 128 + (((2 * fq + h) ^ (r & 7)) * 16);
    }
  #pragma unroll
  for (int n = 0; n < 2; ++n)
    #pragma unroll
    for (int h = 0; h < 2; ++h) {
      const int r = wc * 32 + n * 16 + fr;
      offB8[n][h] = r * 128 + (((2 * fq + h) ^ (r & 7)) * 16);
    }

  f32x4 acc[2][2][4][2];
  #pragma unroll
  for (int i = 0; i < 2; ++i)
    #pragma unroll
    for (int j = 0; j < 2; ++j)
      #pragma unroll
      for (int m = 0; m < 4; ++m)
        #pragma unroll
        for (int n = 0; n < 2; ++n)
          #pragma unroll
          for (int r = 0; r < 4; ++r) acc[i][j][m][n][r] = 0.f;

  i32x8 af8[4], bv8[2][2];
  const int NT = K >> 7;

  STAGE8(0, 0, sA0, lda, 0); STAGE8(0, 1, sA1, lda, 0);
  STAGE8(0, 2, sB0, ldb, 0); STAGE8(0, 3, sB1, ldb, 0);
  STAGE8(1, 0, sA0, lda, 128); STAGE8(1, 3, sB1, ldb, 128); STAGE8(1, 1, sA1, lda, 128);
  asm volatile("s_waitcnt vmcnt(6)" ::: "memory");
  __builtin_amdgcn_s_barrier();

  int b = 0;
  for (int t = 0; t < NT; ++t, b ^= 1) {
    const int nb = b ^ 1;
    const long long k1 = (long long)(t + 1) << 7;
    const long long k2 = (long long)(t + 2) << 7;

    LDA_FRAGS8(b, 0)
    LDB_FRAGS8(b, 0)
    if (t + 1 < NT) STAGE8(nb, 2, sB0, ldb, k1);
    PHASE_MID();
    MFMA_Q8(0, 0)
    PHASE_END();

    LDB_FRAGS8(b, 1)
    if (t + 2 < NT) STAGE8(b, 0, sA0, lda, k2);
    PHASE_MID();
    MFMA_Q8(0, 1)
    PHASE_END();

    LDA_FRAGS8(b, 1)
    if (t + 2 < NT) STAGE8(b, 3, sB1, ldb, k2);
    PHASE_MID();
    MFMA_Q8(1, 1)
    PHASE_END();

    if (t + 2 < NT) STAGE8(b, 1, sA1, lda, k2);
    PHASE_MID();
    MFMA_Q8(1, 0)
    __builtin_amdgcn_s_setprio(0);
    if (t < NT - 1) {
      if (t <= NT - 3) asm volatile("s_waitcnt vmcnt(6)" ::: "memory");
      else             asm volatile("s_waitcnt vmcnt(0)" ::: "memory");
    }
    asm volatile("" ::: "memory");
    __builtin_amdgcn_s_barrier();
  }

  #pragma unroll
  for (int qm = 0; qm < 2; ++qm)
    #pragma unroll
    for (int qn = 0; qn < 2; ++qn)
      #pragma unroll
      for (int m = 0; m < 4; ++m)
        #pragma unroll
        for (int n = 0; n < 2; ++n) {
          const int row0 = bm * 256 + qm * 128 + wr * 64 + m * 16 + fq * 4;
          const int col  = bn * 256 + qn * 128 + wc * 32 + n * 16 + fr;
          const float bb = (OMODE == 2) ? bias[col] : 0.f;
          #pragma unroll
          for (int r = 0; r < 4; ++r) {
            const float v = acc[qm][qn][m][n][r] * rescale + bb;
            if (OMODE == 0)
              ((unsigned char*)Cv)[(long long)(row0 + r) * ldc + col] = to_fp8(v);
            else
              ((float*)Cv)[(long long)(row0 + r) * ldc + col] = v;
          }
        }
}

// ---------------- row softmax (bf16 scores in, A-f32 + A-fp8x256 out) ----------------
__device__ __forceinline__ float wred_max(float v) {
  #pragma unroll
  for (int o = 32; o; o >>= 1) v = fmaxf(v, __shfl_xor(v, o, 64));
  return v;
}
__device__ __forceinline__ float wred_sum(float v) {
  #pragma unroll
  for (int o = 32; o; o >>= 1) v += __shfl_xor(v, o, 64);
  return v;
}

__global__ __launch_bounds__(256)
void softmax_rows(bf16_t* Abf, float* __restrict__ Aout) {
  const int m = blockIdx.x;          // 0..8191
  const int q = m & (SEQ - 1);
  const int t = threadIdx.x;
  const int base = t * 8;
  bf16_t* srow = Abf + (long long)m * SEQ;

  bf16x8 sv = *(const bf16x8*)(srow + base);
  float v[8];
  float mx = -INFINITY;
  #pragma unroll
  for (int i = 0; i < 8; i++) {
    v[i] = (base + i <= q) ? (float)sv[i] : -INFINITY;
    mx = fmaxf(mx, v[i]);
  }
  __shared__ float redm[4], reds[4];
  const int lane = t & 63, w = t >> 6;
  float wm = wred_max(mx);
  if (lane == 0) redm[w] = wm;
  __syncthreads();
  mx = fmaxf(fmaxf(redm[0], redm[1]), fmaxf(redm[2], redm[3]));

  float e[8]; float s = 0.f;
  #pragma unroll
  for (int i = 0; i < 8; i++) {
    e[i] = (base + i <= q) ? __expf(v[i] - mx) : 0.f;
    s += e[i];
  }
  float wsu = wred_sum(s);
  if (lane == 0) reds[w] = wsu;
  __syncthreads();                 // all loads complete before any store below
  s = reds[0] + reds[1] + reds[2] + reds[3];
  const float inv = 1.f / s;

  f32x4 o0, o1;
  float av[8];
  #pragma unroll
  for (int i = 0; i < 8; i++) av[i] = e[i] * inv;
  o0[0] = av[0]; o0[1] = av[1]; o0[2] = av[2]; o0[3] = av[3];
  o1[0] = av[4]; o1[1] = av[5]; o1[2] = av[6]; o1[3] = av[7];
  float* orow = Aout + (long long)m * SEQ;
  __builtin_nontemporal_store(o0, (f32x4*)(orow) + t * 2);
  __builtin_nontemporal_store(o1, (f32x4*)(orow) + t * 2 + 1);

  // A8 = fp8(A*256), in place over the scores row
  int lo = 0, hi = 0;
  lo = __builtin_amdgcn_cvt_pk_fp8_f32(av[0] * 256.f, av[1] * 256.f, lo, false);
  lo = __builtin_amdgcn_cvt_pk_fp8_f32(av[2] * 256.f, av[3] * 256.f, lo, true);
  hi = __builtin_amdgcn_cvt_pk_fp8_f32(av[4] * 256.f, av[5] * 256.f, hi, false);
  hi = __builtin_amdgcn_cvt_pk_fp8_f32(av[6] * 256.f, av[7] * 256.f, hi, true);
  *(int2*)((unsigned char*)srow + base) = make_int2(lo, hi);
}

// ---------------- launch ----------------
extern "C" void kernel_launch(void* const* d_in, const int* in_sizes, int n_in,
                              void* d_out, int out_size, void* d_ws, size_t ws_size,
                              hipStream_t stream) {
  const int*   idx   = (const int*)d_in[0];
  const float* embed = (const float*)d_in[1];
  const float* Wq    = (const float*)d_in[2];
  const float* Wk    = (const float*)d_in[3];
  const float* Wv    = (const float*)d_in[4];
  const float* Wout  = (const float*)d_in[5];
  const float* bout  = (const float*)d_in[6];

  float* out = (float*)d_out;
  char*  ws  = (char*)d_ws;

  unsigned char* Wqkv8 = (unsigned char*)(ws + WQKV_OFF);
  unsigned char* Wout8 = (unsigned char*)(ws + WOUT_OFF);
  unsigned char* Ao8   = (unsigned char*)(ws + AO8_OFF);
  unsigned char* X8    = (unsigned char*)(ws + X8_OFF);
  unsigned char* QKV8  = (unsigned char*)(ws + QKV8_OFF);
  unsigned char* Vt8   = (unsigned char*)(ws + VT_OFF);
  bf16_t*        Abf   = (bf16_t*)(ws + ABF_OFF);   // scores bf16; A8 fp8 in place
  float*         Aout  = out + LOGITS_ELEMS;

  // weight quants (x64 for QKV weights, x32 for Wout)
  quant_fp8_f32<<<512, 256, 0, stream>>>(Wq, (int2*)(Wqkv8),            131072, 64.f);
  quant_fp8_f32<<<512, 256, 0, stream>>>(Wk, (int2*)(Wqkv8 + 1048576),  131072, 64.f);
  quant_fp8_f32<<<512, 256, 0, stream>>>(Wv, (int2*)(Wqkv8 + 2097152),  131072, 64.f);
  quant_fp8_f32<<<2048, 256, 0, stream>>>(Wout, (int2*)Wout8, 4096000, 32.f);

  // x8 = fp8(embed[idx] * 64)
  gather_fp8<<<8192, 256, 0, stream>>>(idx, embed, X8);

  // QKV8 = fp8((X8 @ Wqkv8^T)/64)   (256² 8-phase fp8, 32bm x 12bn)
  gemm256_fp8<0><<<dim3(384), 512, 0, stream>>>(
      X8, Wqkv8, QKV8, nullptr, 1024, 1024, 1024, 3072, 12, 1.f / 64.f);

  // Vt8[b][d][s]
  transpose_v8<<<dim3(32, 16, 4), 256, 0, stream>>>(QKV8, Vt8);

  // scores bf16 = (Q.K^T) * 2^-17, causal tiles only
  gemm_bt_fp8<3, true, false><<<dim3(16, 16, 4), 256, 0, stream>>>(
      QKV8, QKV8 + 1024, Abf, 1024, 3072, 3072, 2048,
      2048LL * 3072, 2048LL * 3072, 2048LL * 2048, 1.f / 131072.f);

  // softmax: A f32 -> d_out, A8 = fp8(A*256) in place
  softmax_rows<<<8192, 256, 0, stream>>>(Abf, Aout);

  // Ao8 = fp8(attn_out * 256) = fp8(acc/64)   (K trimmed to causal extent)
  gemm_bt_fp8<0, false, true><<<dim3(8, 16, 4), 256, 0, stream>>>(
      (unsigned char*)Abf, Vt8, Ao8, 2048, 4096, 2048, 1024,
      2048LL * 4096, 1024LL * 2048, 2048LL * 1024, 1.f / 64.f);

  // logits = attn_out @ Wout^T + bout  (128² dbuf fp8, 2-3 blocks/CU)
  gemm128_fp8_dbuf<<<dim3(250, 64), 256, 0, stream>>>(
      Ao8, Wout8, out, bout, 1024, 1024, 1024, VOCAB, 1.f / 8192.f);
}

// Round 9
// 632.337 us; speedup vs baseline: 1.0881x; 1.0881x over previous
//
#include <hip/hip_runtime.h>
#include <hip/hip_bf16.h>
#include <cmath>
#include <cstdint>

typedef __bf16 bf16_t;
typedef bf16_t bf16x8 __attribute__((ext_vector_type(8)));
typedef float  f32x4  __attribute__((ext_vector_type(4)));
typedef int    i32x4  __attribute__((ext_vector_type(4)));
typedef int    i32x8  __attribute__((ext_vector_type(8)));

#define VOCAB 32000
#define DDIM  1024
#define BATCH 4
#define SEQ   2048
#define MTOT  (BATCH*SEQ)                       // 8192
#define LOGITS_ELEMS (262144000LL)              // MTOT*VOCAB

// ---- ws layout (bytes) ----
#define WQKV_OFF 0LL                            // Wqkv8 fp8 [3072][1024] (3MB)
#define WOUT_OFF 6291456LL                      // Wout8 fp8 [32000][1024] (32MB)
#define AO8_OFF  (WOUT_OFF + 33554432LL)        // Ao8 fp8 [8192][1024] (8MB)
#define X8_OFF   71827456LL                     // X8 fp8 [8192][1024] (8MB)
#define QKV8_OFF 88604672LL                     // QKV8 fp8 [8192][3072] (24MB)
#define VT_OFF   138936320LL                    // Vt8 fp8 [4][1024][2048] (8MB)
#define ABF_OFF  155713536LL                    // scores bf16 [4][2048][2048]; A8 fp8 in place
// END = 189267968 bytes required in ws

#define SC127 0x7F7F7F7F                        // E8M0 identity scales (2^0)

__device__ __forceinline__ void gl_lds16(const void* g, void* l) {
  __builtin_amdgcn_global_load_lds(
      (const __attribute__((address_space(1))) void*)g,
      (__attribute__((address_space(3))) void*)l, 16, 0, 0);
}

__device__ __forceinline__ i32x8 join8(i32x4 lo, i32x4 hi) {
  i32x8 r;
  r[0] = lo[0]; r[1] = lo[1]; r[2] = lo[2]; r[3] = lo[3];
  r[4] = hi[0]; r[5] = hi[1]; r[6] = hi[2]; r[7] = hi[3];
  return r;
}

__device__ __forceinline__ unsigned char to_fp8(float v) {
  int p = __builtin_amdgcn_cvt_pk_fp8_f32(v, v, 0, false);
  return (unsigned char)(p & 0xFF);
}

// ---------------- f32 -> fp8(e4m3) quant, software pow-2 scale ----------------
__global__ __launch_bounds__(256)
void quant_fp8_f32(const float* __restrict__ s, int2* __restrict__ d, int n8, float scale) {
  int i = blockIdx.x * 256 + threadIdx.x;
  const int stride = gridDim.x * 256;
  for (; i < n8; i += stride) {
    float4 a = ((const float4*)s)[i * 2];
    float4 b = ((const float4*)s)[i * 2 + 1];
    int lo = 0, hi = 0;
    lo = __builtin_amdgcn_cvt_pk_fp8_f32(a.x * scale, a.y * scale, lo, false);
    lo = __builtin_amdgcn_cvt_pk_fp8_f32(a.z * scale, a.w * scale, lo, true);
    hi = __builtin_amdgcn_cvt_pk_fp8_f32(b.x * scale, b.y * scale, hi, false);
    hi = __builtin_amdgcn_cvt_pk_fp8_f32(b.z * scale, b.w * scale, hi, true);
    d[i] = make_int2(lo, hi);
  }
}

// ---------------- embedding gather + fp8 quant (x64) ----------------
__global__ __launch_bounds__(256)
void gather_fp8(const int* __restrict__ idx, const float* __restrict__ embed,
                unsigned char* __restrict__ X8) {
  const int m = blockIdx.x;
  const int row = idx[m];
  float4 v = ((const float4*)(embed + (long long)row * DDIM))[threadIdx.x];
  int p = 0;
  p = __builtin_amdgcn_cvt_pk_fp8_f32(v.x * 64.f, v.y * 64.f, p, false);
  p = __builtin_amdgcn_cvt_pk_fp8_f32(v.z * 64.f, v.w * 64.f, p, true);
  ((int*)(X8 + (long long)m * DDIM))[threadIdx.x] = p;
}

// ---------------- V transpose (bytes): QKV8 cols[2048..3071] -> Vt8[b][d][s] ----------------
__global__ __launch_bounds__(256)
void transpose_v8(const unsigned char* __restrict__ QKV8, unsigned char* __restrict__ Vt8) {
  __shared__ unsigned char tile[64][68];
  const int b = blockIdx.z;
  const int s0 = blockIdx.x * 64, d0 = blockIdx.y * 64;
  const int tx = threadIdx.x & 63, ty = threadIdx.x >> 6;
  #pragma unroll
  for (int i = ty; i < 64; i += 4)
    tile[i][tx] = QKV8[((long long)(b * SEQ + s0 + i)) * 3072 + 2048 + d0 + tx];
  __syncthreads();
  #pragma unroll
  for (int i = ty; i < 64; i += 4)
    Vt8[((long long)(b * DDIM + d0 + i)) * SEQ + s0 + tx] = tile[tx][i];
}

// ---------------- 128x128 fp8 BT-GEMM, single-buffer (scores / PV) ----------------
// OMODE: 0 = fp8 out (v*rescale), 3 = bf16 out (v*rescale).
template<int OMODE, bool CSKIP, bool CTRIM>
__global__ __launch_bounds__(256)
void gemm_bt_fp8(const unsigned char* __restrict__ A, const unsigned char* __restrict__ B,
                 void* __restrict__ Cv, int K, int lda, int ldb, int ldc,
                 long long sA, long long sB, long long sC, float rescale) {
  const int bn = blockIdx.x, bm = blockIdx.y, bz = blockIdx.z;
  if (CSKIP && bn > bm) return;

  __shared__ unsigned char As8[128 * 128];
  __shared__ unsigned char Bs8[128 * 128];

  const int t = threadIdx.x;
  const int lane = t & 63;
  const int w = t >> 6;
  const int wr = w >> 1, wc = w & 1;
  const int fr = lane & 15, fq = lane >> 4;

  f32x4 acc[4][4];
  #pragma unroll
  for (int m = 0; m < 4; m++)
    #pragma unroll
    for (int n = 0; n < 4; n++)
      #pragma unroll
      for (int r = 0; r < 4; r++) acc[m][n][r] = 0.f;

  int kEnd = K;
  if (CTRIM) { int ke = (bm + 1) * 128; kEnd = ke < K ? ke : K; }

  const unsigned char* Ab = A + bz * sA + (long long)(bm * 128) * lda;
  const unsigned char* Bb = B + bz * sB + (long long)(bn * 128) * ldb;

  const int srow = t >> 3;                       // 0..31
  const int gsw = ((t & 7) ^ (srow & 7)) * 16;   // pre-swizzled source granule

  int offA8[4][2], offB8[4][2];
  #pragma unroll
  for (int m = 0; m < 4; ++m)
    #pragma unroll
    for (int h = 0; h < 2; ++h) {
      const int r = wr * 64 + m * 16 + fr;
      offA8[m][h] = r * 128 + (((2 * fq + h) ^ (r & 7)) * 16);
    }
  #pragma unroll
  for (int n = 0; n < 4; ++n)
    #pragma unroll
    for (int h = 0; h < 2; ++h) {
      const int r = wc * 64 + n * 16 + fr;
      offB8[n][h] = r * 128 + (((2 * fq + h) ^ (r & 7)) * 16);
    }

  for (int k0 = 0; k0 < kEnd; k0 += 128) {
    #pragma unroll
    for (int p = 0; p < 4; ++p) {
      gl_lds16(Ab + (long long)(p * 32 + srow) * lda + k0 + gsw, &As8[p * 4096 + t * 16]);
      gl_lds16(Bb + (long long)(p * 32 + srow) * ldb + k0 + gsw, &Bs8[p * 4096 + t * 16]);
    }
    __syncthreads();

    i32x8 af8[4], bv8[4];
    #pragma unroll
    for (int m = 0; m < 4; ++m)
      af8[m] = join8(*(const i32x4*)&As8[offA8[m][0]], *(const i32x4*)&As8[offA8[m][1]]);
    #pragma unroll
    for (int n = 0; n < 4; ++n)
      bv8[n] = join8(*(const i32x4*)&Bs8[offB8[n][0]], *(const i32x4*)&Bs8[offB8[n][1]]);
    #pragma unroll
    for (int m = 0; m < 4; ++m)
      #pragma unroll
      for (int n = 0; n < 4; ++n)
        acc[m][n] = __builtin_amdgcn_mfma_scale_f32_16x16x128_f8f6f4(
            af8[m], bv8[n], acc[m][n], 0, 0, 0, SC127, 0, SC127);
    __syncthreads();
  }

  const int row0 = bm * 128 + wr * 64 + fq * 4;
  const int col0 = bn * 128 + wc * 64 + fr;
  #pragma unroll
  for (int m = 0; m < 4; m++)
    #pragma unroll
    for (int n = 0; n < 4; n++) {
      const int col = col0 + n * 16;
      #pragma unroll
      for (int r = 0; r < 4; r++) {
        const int row = row0 + m * 16 + r;
        const float v = acc[m][n][r] * rescale;
        if (OMODE == 0)
          ((unsigned char*)Cv)[bz * sC + (long long)row * ldc + col] = to_fp8(v);
        else
          ((bf16_t*)Cv)[bz * sC + (long long)row * ldc + col] = (bf16_t)v;
      }
    }
}

// ---------------- shared phase-sync macros (256² 8-phase) ----------------
#define PHASE_MID() do {                                                  \
    asm volatile("" ::: "memory");                                        \
    __builtin_amdgcn_s_barrier();                                         \
    asm volatile("s_waitcnt lgkmcnt(0)" ::: "memory");                    \
    __builtin_amdgcn_sched_barrier(0);                                    \
    __builtin_amdgcn_s_setprio(1);                                        \
  } while (0)

#define PHASE_END() do {                                                  \
    __builtin_amdgcn_s_setprio(0);                                        \
    asm volatile("" ::: "memory");                                        \
    __builtin_amdgcn_s_barrier();                                         \
  } while (0)

// ---------------- 256x256 8-phase MX-fp8 BT-GEMM (QKV / logits) ----------------
// OMODE 0: fp8 out (v*rescale); OMODE 2: f32 out + bias via LDS-restaged
// coalesced epilogue (full 512B contiguous row segments, plain stores).
#define STAGE8(buf, h, src, ld, k0) do {                                  \
    gl_lds16((src) + (k0), &lds8[buf][h][tt * 16]);                       \
    gl_lds16((src) + (long long)64 * (ld) + (k0), &lds8[buf][h][8192 + tt * 16]); \
  } while (0)

#define LDA_FRAGS8(buf, qm)                                               \
  _Pragma("unroll") for (int m_ = 0; m_ < 4; ++m_) {                      \
    i32x4 lo_ = *(const i32x4*)&lds8[buf][qm][offA8[m_][0]];              \
    i32x4 hi_ = *(const i32x4*)&lds8[buf][qm][offA8[m_][1]];              \
    af8[m_] = join8(lo_, hi_);                                            \
  }

#define LDB_FRAGS8(buf, qn)                                               \
  _Pragma("unroll") for (int n_ = 0; n_ < 2; ++n_) {                      \
    i32x4 lo_ = *(const i32x4*)&lds8[buf][2 + (qn)][offB8[n_][0]];        \
    i32x4 hi_ = *(const i32x4*)&lds8[buf][2 + (qn)][offB8[n_][1]];        \
    bv8[qn][n_] = join8(lo_, hi_);                                        \
  }

#define MFMA_Q8(qm, qn)                                                   \
  _Pragma("unroll") for (int m_ = 0; m_ < 4; ++m_)                        \
  _Pragma("unroll") for (int n_ = 0; n_ < 2; ++n_)                        \
    acc[qm][qn][m_][n_] = __builtin_amdgcn_mfma_scale_f32_16x16x128_f8f6f4( \
        af8[m_], bv8[qn][n_], acc[qm][qn][m_][n_], 0, 0, 0, SC127, 0, SC127);

template<int OMODE>
__global__ __launch_bounds__(512, 2)
void gemm256_fp8(const unsigned char* __restrict__ A, const unsigned char* __restrict__ B,
                 void* __restrict__ Cv, const float* __restrict__ bias,
                 int K, int lda, int ldb, int ldc, int nbn, float rescale) {
  __shared__ unsigned char lds8[2][4][16384];

  const int nwg = gridDim.x;
  const int bid = blockIdx.x;
  const int swz = (nwg & 7) ? bid : ((bid & 7) * (nwg >> 3) + (bid >> 3));
  const int per_group = 8 * nbn;
  const int g   = swz / per_group;
  const int rem = swz - g * per_group;
  const int bm = g * 8 + (rem & 7);
  const int bn = rem >> 3;

  const int tt = threadIdx.x;
  const int lane = tt & 63;
  const int w = tt >> 6;
  const int wr = w >> 2, wc = w & 3;
  const int fr = lane & 15, fq = lane >> 4;

  const int srow = tt >> 3;
  const int gl = (tt & 7) ^ (srow & 7);
  const unsigned char* sA0 = A + (long long)(bm * 256 +       srow) * lda + gl * 16;
  const unsigned char* sA1 = A + (long long)(bm * 256 + 128 + srow) * lda + gl * 16;
  const unsigned char* sB0 = B + (long long)(bn * 256 +       srow) * ldb + gl * 16;
  const unsigned char* sB1 = B + (long long)(bn * 256 + 128 + srow) * ldb + gl * 16;

  int offA8[4][2], offB8[2][2];
  #pragma unroll
  for (int m = 0; m < 4; ++m)
    #pragma unroll
    for (int h = 0; h < 2; ++h) {
      const int r = wr * 64 + m * 16 + fr;
      offA8[m][h] = r * 128 + (((2 * fq + h) ^ (r & 7)) * 16);
    }
  #pragma unroll
  for (int n = 0; n < 2; ++n)
    #pragma unroll
    for (int h = 0; h < 2; ++h) {
      const int r = wc * 32 + n * 16 + fr;
      offB8[n][h] = r * 128 + (((2 * fq + h) ^ (r & 7)) * 16);
    }

  f32x4 acc[2][2][4][2];
  #pragma unroll
  for (int i = 0; i < 2; ++i)
    #pragma unroll
    for (int j = 0; j < 2; ++j)
      #pragma unroll
      for (int m = 0; m < 4; ++m)
        #pragma unroll
        for (int n = 0; n < 2; ++n)
          #pragma unroll
          for (int r = 0; r < 4; ++r) acc[i][j][m][n][r] = 0.f;

  i32x8 af8[4], bv8[2][2];
  const int NT = K >> 7;

  STAGE8(0, 0, sA0, lda, 0); STAGE8(0, 1, sA1, lda, 0);
  STAGE8(0, 2, sB0, ldb, 0); STAGE8(0, 3, sB1, ldb, 0);
  STAGE8(1, 0, sA0, lda, 128); STAGE8(1, 3, sB1, ldb, 128); STAGE8(1, 1, sA1, lda, 128);
  asm volatile("s_waitcnt vmcnt(6)" ::: "memory");
  __builtin_amdgcn_s_barrier();

  int b = 0;
  for (int t = 0; t < NT; ++t, b ^= 1) {
    const int nb = b ^ 1;
    const long long k1 = (long long)(t + 1) << 7;
    const long long k2 = (long long)(t + 2) << 7;

    LDA_FRAGS8(b, 0)
    LDB_FRAGS8(b, 0)
    if (t + 1 < NT) STAGE8(nb, 2, sB0, ldb, k1);
    PHASE_MID();
    MFMA_Q8(0, 0)
    PHASE_END();

    LDB_FRAGS8(b, 1)
    if (t + 2 < NT) STAGE8(b, 0, sA0, lda, k2);
    PHASE_MID();
    MFMA_Q8(0, 1)
    PHASE_END();

    LDA_FRAGS8(b, 1)
    if (t + 2 < NT) STAGE8(b, 3, sB1, ldb, k2);
    PHASE_MID();
    MFMA_Q8(1, 1)
    PHASE_END();

    if (t + 2 < NT) STAGE8(b, 1, sA1, lda, k2);
    PHASE_MID();
    MFMA_Q8(1, 0)
    __builtin_amdgcn_s_setprio(0);
    if (t < NT - 1) {
      if (t <= NT - 3) asm volatile("s_waitcnt vmcnt(6)" ::: "memory");
      else             asm volatile("s_waitcnt vmcnt(0)" ::: "memory");
    }
    asm volatile("" ::: "memory");
    __builtin_amdgcn_s_barrier();
  }

  if (OMODE == 0) {
    #pragma unroll
    for (int qm = 0; qm < 2; ++qm)
      #pragma unroll
      for (int qn = 0; qn < 2; ++qn)
        #pragma unroll
        for (int m = 0; m < 4; ++m)
          #pragma unroll
          for (int n = 0; n < 2; ++n) {
            const int row0 = bm * 256 + qm * 128 + wr * 64 + m * 16 + fq * 4;
            const int col  = bn * 256 + qn * 128 + wc * 32 + n * 16 + fr;
            #pragma unroll
            for (int r = 0; r < 4; ++r)
              ((unsigned char*)Cv)[(long long)(row0 + r) * ldc + col] =
                  to_fp8(acc[qm][qn][m][n][r] * rescale);
          }
  } else {
    // LDS-restaged coalesced epilogue: per 128x128 quadrant, stage f32 into
    // padded [128][132] LDS (bank-safe), then each half-wave stores one full
    // 512B contiguous row via f32x4 (128B-line-aligned HBM writes).
    float* ep = (float*)lds8;              // 128*132*4 = 66 KB of the dead 128 KB
    const int fl = tt & 31, rg = tt >> 5;  // fl: float4 idx in row; rg: 0..15
    #pragma unroll
    for (int qm = 0; qm < 2; ++qm)
      #pragma unroll
      for (int qn = 0; qn < 2; ++qn) {
        #pragma unroll
        for (int m = 0; m < 4; ++m)
          #pragma unroll
          for (int n = 0; n < 2; ++n) {
            const int lcol = wc * 32 + n * 16 + fr;
            const float bb = bias[bn * 256 + qn * 128 + lcol];
            #pragma unroll
            for (int r = 0; r < 4; ++r)
              ep[(wr * 64 + m * 16 + fq * 4 + r) * 132 + lcol] =
                  acc[qm][qn][m][n][r] * rescale + bb;
          }
        __syncthreads();
        const long long rbase = (long long)(bm * 256 + qm * 128);
        const long long cbase = bn * 256 + qn * 128 + fl * 4;
        #pragma unroll
        for (int i = 0; i < 8; ++i) {
          const int row = rg + i * 16;
          f32x4 v = *(const f32x4*)&ep[row * 132 + fl * 4];
          *(f32x4*)&((float*)Cv)[(rbase + row) * ldc + cbase] = v;
        }
        __syncthreads();
      }
  }
}

// ---------------- row softmax (bf16 scores in, A-f32 + A-fp8x256 out) ----------------
__device__ __forceinline__ float wred_max(float v) {
  #pragma unroll
  for (int o = 32; o; o >>= 1) v = fmaxf(v, __shfl_xor(v, o, 64));
  return v;
}
__device__ __forceinline__ float wred_sum(float v) {
  #pragma unroll
  for (int o = 32; o; o >>= 1) v += __shfl_xor(v, o, 64);
  return v;
}

__global__ __launch_bounds__(256)
void softmax_rows(bf16_t* Abf, float* __restrict__ Aout) {
  const int m = blockIdx.x;          // 0..8191
  const int q = m & (SEQ - 1);
  const int t = threadIdx.x;
  const int base = t * 8;
  bf16_t* srow = Abf + (long long)m * SEQ;

  bf16x8 sv = *(const bf16x8*)(srow + base);
  float v[8];
  float mx = -INFINITY;
  #pragma unroll
  for (int i = 0; i < 8; i++) {
    v[i] = (base + i <= q) ? (float)sv[i] : -INFINITY;
    mx = fmaxf(mx, v[i]);
  }
  __shared__ float redm[4], reds[4];
  const int lane = t & 63, w = t >> 6;
  float wm = wred_max(mx);
  if (lane == 0) redm[w] = wm;
  __syncthreads();
  mx = fmaxf(fmaxf(redm[0], redm[1]), fmaxf(redm[2], redm[3]));

  float e[8]; float s = 0.f;
  #pragma unroll
  for (int i = 0; i < 8; i++) {
    e[i] = (base + i <= q) ? __expf(v[i] - mx) : 0.f;
    s += e[i];
  }
  float wsu = wred_sum(s);
  if (lane == 0) reds[w] = wsu;
  __syncthreads();                 // all loads complete before any store below
  s = reds[0] + reds[1] + reds[2] + reds[3];
  const float inv = 1.f / s;

  f32x4 o0, o1;
  float av[8];
  #pragma unroll
  for (int i = 0; i < 8; i++) av[i] = e[i] * inv;
  o0[0] = av[0]; o0[1] = av[1]; o0[2] = av[2]; o0[3] = av[3];
  o1[0] = av[4]; o1[1] = av[5]; o1[2] = av[6]; o1[3] = av[7];
  float* orow = Aout + (long long)m * SEQ;
  __builtin_nontemporal_store(o0, (f32x4*)(orow) + t * 2);
  __builtin_nontemporal_store(o1, (f32x4*)(orow) + t * 2 + 1);

  // A8 = fp8(A*256), in place over the scores row
  int lo = 0, hi = 0;
  lo = __builtin_amdgcn_cvt_pk_fp8_f32(av[0] * 256.f, av[1] * 256.f, lo, false);
  lo = __builtin_amdgcn_cvt_pk_fp8_f32(av[2] * 256.f, av[3] * 256.f, lo, true);
  hi = __builtin_amdgcn_cvt_pk_fp8_f32(av[4] * 256.f, av[5] * 256.f, hi, false);
  hi = __builtin_amdgcn_cvt_pk_fp8_f32(av[6] * 256.f, av[7] * 256.f, hi, true);
  *(int2*)((unsigned char*)srow + base) = make_int2(lo, hi);
}

// ---------------- launch ----------------
extern "C" void kernel_launch(void* const* d_in, const int* in_sizes, int n_in,
                              void* d_out, int out_size, void* d_ws, size_t ws_size,
                              hipStream_t stream) {
  const int*   idx   = (const int*)d_in[0];
  const float* embed = (const float*)d_in[1];
  const float* Wq    = (const float*)d_in[2];
  const float* Wk    = (const float*)d_in[3];
  const float* Wv    = (const float*)d_in[4];
  const float* Wout  = (const float*)d_in[5];
  const float* bout  = (const float*)d_in[6];

  float* out = (float*)d_out;
  char*  ws  = (char*)d_ws;

  unsigned char* Wqkv8 = (unsigned char*)(ws + WQKV_OFF);
  unsigned char* Wout8 = (unsigned char*)(ws + WOUT_OFF);
  unsigned char* Ao8   = (unsigned char*)(ws + AO8_OFF);
  unsigned char* X8    = (unsigned char*)(ws + X8_OFF);
  unsigned char* QKV8  = (unsigned char*)(ws + QKV8_OFF);
  unsigned char* Vt8   = (unsigned char*)(ws + VT_OFF);
  bf16_t*        Abf   = (bf16_t*)(ws + ABF_OFF);   // scores bf16; A8 fp8 in place
  float*         Aout  = out + LOGITS_ELEMS;

  // weight quants (x64 for QKV weights, x32 for Wout)
  quant_fp8_f32<<<512, 256, 0, stream>>>(Wq, (int2*)(Wqkv8),            131072, 64.f);
  quant_fp8_f32<<<512, 256, 0, stream>>>(Wk, (int2*)(Wqkv8 + 1048576),  131072, 64.f);
  quant_fp8_f32<<<512, 256, 0, stream>>>(Wv, (int2*)(Wqkv8 + 2097152),  131072, 64.f);
  quant_fp8_f32<<<2048, 256, 0, stream>>>(Wout, (int2*)Wout8, 4096000, 32.f);

  // x8 = fp8(embed[idx] * 64)
  gather_fp8<<<8192, 256, 0, stream>>>(idx, embed, X8);

  // QKV8 = fp8((X8 @ Wqkv8^T)/64)   (256² 8-phase fp8, 32bm x 12bn)
  gemm256_fp8<0><<<dim3(384), 512, 0, stream>>>(
      X8, Wqkv8, QKV8, nullptr, 1024, 1024, 1024, 3072, 12, 1.f / 64.f);

  // Vt8[b][d][s]
  transpose_v8<<<dim3(32, 16, 4), 256, 0, stream>>>(QKV8, Vt8);

  // scores bf16 = (Q.K^T) * 2^-17, causal tiles only
  gemm_bt_fp8<3, true, false><<<dim3(16, 16, 4), 256, 0, stream>>>(
      QKV8, QKV8 + 1024, Abf, 1024, 3072, 3072, 2048,
      2048LL * 3072, 2048LL * 3072, 2048LL * 2048, 1.f / 131072.f);

  // softmax: A f32 -> d_out, A8 = fp8(A*256) in place
  softmax_rows<<<8192, 256, 0, stream>>>(Abf, Aout);

  // Ao8 = fp8(attn_out * 256) = fp8(acc/64)   (K trimmed to causal extent)
  gemm_bt_fp8<0, false, true><<<dim3(8, 16, 4), 256, 0, stream>>>(
      (unsigned char*)Abf, Vt8, Ao8, 2048, 4096, 2048, 1024,
      2048LL * 4096, 1024LL * 2048, 2048LL * 1024, 1.f / 64.f);

  // logits = attn_out @ Wout^T + bout  (MX-fp8 256² 8-phase, 32bm x 125bn,
  // LDS-restaged coalesced epilogue)
  gemm256_fp8<2><<<dim3(4000), 512, 0, stream>>>(
      Ao8, Wout8, out, bout, 1024, 1024, 1024, VOCAB, 125, 1.f / 8192.f);
}

// Round 10
// 616.661 us; speedup vs baseline: 1.1158x; 1.0254x over previous
//
#include <hip/hip_runtime.h>
#include <hip/hip_bf16.h>
#include <cmath>
#include <cstdint>

typedef __bf16 bf16_t;
typedef bf16_t bf16x8 __attribute__((ext_vector_type(8)));
typedef float  f32x4  __attribute__((ext_vector_type(4)));
typedef int    i32x4  __attribute__((ext_vector_type(4)));
typedef int    i32x8  __attribute__((ext_vector_type(8)));

#define VOCAB 32000
#define DDIM  1024
#define BATCH 4
#define SEQ   2048
#define MTOT  (BATCH*SEQ)                       // 8192
#define LOGITS_ELEMS (262144000LL)              // MTOT*VOCAB

// ---- ws layout (bytes) ----
#define WQKV_OFF 0LL                            // Wqkv8 fp8 [3072][1024] (3MB)
#define WOUT_OFF 6291456LL                      // Wout8 fp8 [32000][1024] (32MB)
#define AO8_OFF  (WOUT_OFF + 33554432LL)        // Ao8 fp8 [8192][1024] (8MB)
#define X8_OFF   71827456LL                     // X8 fp8 [8192][1024] (8MB)
#define QKV8_OFF 88604672LL                     // QKV8 fp8 [8192][3072] (24MB)
#define VT_OFF   138936320LL                    // Vt8 fp8 [4][1024][2048] (8MB)
#define ABF_OFF  155713536LL                    // scores bf16 [4][2048][2048]; A8 fp8 in place
// END = 189267968 bytes required in ws

#define SC127 0x7F7F7F7F                        // E8M0 identity scales (2^0)

__device__ __forceinline__ void gl_lds16(const void* g, void* l) {
  __builtin_amdgcn_global_load_lds(
      (const __attribute__((address_space(1))) void*)g,
      (__attribute__((address_space(3))) void*)l, 16, 0, 0);
}

__device__ __forceinline__ i32x8 join8(i32x4 lo, i32x4 hi) {
  i32x8 r;
  r[0] = lo[0]; r[1] = lo[1]; r[2] = lo[2]; r[3] = lo[3];
  r[4] = hi[0]; r[5] = hi[1]; r[6] = hi[2]; r[7] = hi[3];
  return r;
}

__device__ __forceinline__ unsigned char to_fp8(float v) {
  int p = __builtin_amdgcn_cvt_pk_fp8_f32(v, v, 0, false);
  return (unsigned char)(p & 0xFF);
}

// ---------------- f32 -> fp8(e4m3) quant, software pow-2 scale ----------------
__global__ __launch_bounds__(256)
void quant_fp8_f32(const float* __restrict__ s, int2* __restrict__ d, int n8, float scale) {
  int i = blockIdx.x * 256 + threadIdx.x;
  const int stride = gridDim.x * 256;
  for (; i < n8; i += stride) {
    float4 a = ((const float4*)s)[i * 2];
    float4 b = ((const float4*)s)[i * 2 + 1];
    int lo = 0, hi = 0;
    lo = __builtin_amdgcn_cvt_pk_fp8_f32(a.x * scale, a.y * scale, lo, false);
    lo = __builtin_amdgcn_cvt_pk_fp8_f32(a.z * scale, a.w * scale, lo, true);
    hi = __builtin_amdgcn_cvt_pk_fp8_f32(b.x * scale, b.y * scale, hi, false);
    hi = __builtin_amdgcn_cvt_pk_fp8_f32(b.z * scale, b.w * scale, hi, true);
    d[i] = make_int2(lo, hi);
  }
}

// ---------------- Wq/Wk/Wv -> fp8 in one launch (x64) ----------------
__global__ __launch_bounds__(256)
void quant_fp8_qkv(const float* __restrict__ Wq, const float* __restrict__ Wk,
                   const float* __restrict__ Wv, int2* __restrict__ d) {
  // 3 x 131072 int2-groups (each int2 = 8 elems); 393216 total
  int i = blockIdx.x * 256 + threadIdx.x;
  const int stride = gridDim.x * 256;
  for (; i < 393216; i += stride) {
    const int sel = i >> 17;                 // 0,1,2
    const int j = i & 131071;
    const float* s = (sel == 0) ? Wq : (sel == 1) ? Wk : Wv;
    float4 a = ((const float4*)s)[j * 2];
    float4 b = ((const float4*)s)[j * 2 + 1];
    int lo = 0, hi = 0;
    lo = __builtin_amdgcn_cvt_pk_fp8_f32(a.x * 64.f, a.y * 64.f, lo, false);
    lo = __builtin_amdgcn_cvt_pk_fp8_f32(a.z * 64.f, a.w * 64.f, lo, true);
    hi = __builtin_amdgcn_cvt_pk_fp8_f32(b.x * 64.f, b.y * 64.f, hi, false);
    hi = __builtin_amdgcn_cvt_pk_fp8_f32(b.z * 64.f, b.w * 64.f, hi, true);
    d[i] = make_int2(lo, hi);
  }
}

// ---------------- embedding gather + fp8 quant (x64) ----------------
__global__ __launch_bounds__(256)
void gather_fp8(const int* __restrict__ idx, const float* __restrict__ embed,
                unsigned char* __restrict__ X8) {
  const int m = blockIdx.x;
  const int row = idx[m];
  float4 v = ((const float4*)(embed + (long long)row * DDIM))[threadIdx.x];
  int p = 0;
  p = __builtin_amdgcn_cvt_pk_fp8_f32(v.x * 64.f, v.y * 64.f, p, false);
  p = __builtin_amdgcn_cvt_pk_fp8_f32(v.z * 64.f, v.w * 64.f, p, true);
  ((int*)(X8 + (long long)m * DDIM))[threadIdx.x] = p;
}

// ---------------- V transpose (bytes): QKV8 cols[2048..3071] -> Vt8[b][d][s] ----------------
__global__ __launch_bounds__(256)
void transpose_v8(const unsigned char* __restrict__ QKV8, unsigned char* __restrict__ Vt8) {
  __shared__ unsigned char tile[64][68];
  const int b = blockIdx.z;
  const int s0 = blockIdx.x * 64, d0 = blockIdx.y * 64;
  const int tx = threadIdx.x & 63, ty = threadIdx.x >> 6;
  #pragma unroll
  for (int i = ty; i < 64; i += 4)
    tile[i][tx] = QKV8[((long long)(b * SEQ + s0 + i)) * 3072 + 2048 + d0 + tx];
  __syncthreads();
  #pragma unroll
  for (int i = ty; i < 64; i += 4)
    Vt8[((long long)(b * DDIM + d0 + i)) * SEQ + s0 + tx] = tile[tx][i];
}

// ---------------- 128x128 fp8 BT-GEMM, single-buffer (scores / PV) ----------------
// OMODE: 0 = fp8 out (v*rescale), 3 = bf16 out (v*rescale).
template<int OMODE, bool CSKIP, bool CTRIM>
__global__ __launch_bounds__(256)
void gemm_bt_fp8(const unsigned char* __restrict__ A, const unsigned char* __restrict__ B,
                 void* __restrict__ Cv, int K, int lda, int ldb, int ldc,
                 long long sA, long long sB, long long sC, float rescale) {
  const int bn = blockIdx.x, bm = blockIdx.y, bz = blockIdx.z;
  if (CSKIP && bn > bm) return;

  __shared__ unsigned char As8[128 * 128];
  __shared__ unsigned char Bs8[128 * 128];

  const int t = threadIdx.x;
  const int lane = t & 63;
  const int w = t >> 6;
  const int wr = w >> 1, wc = w & 1;
  const int fr = lane & 15, fq = lane >> 4;

  f32x4 acc[4][4];
  #pragma unroll
  for (int m = 0; m < 4; m++)
    #pragma unroll
    for (int n = 0; n < 4; n++)
      #pragma unroll
      for (int r = 0; r < 4; r++) acc[m][n][r] = 0.f;

  int kEnd = K;
  if (CTRIM) { int ke = (bm + 1) * 128; kEnd = ke < K ? ke : K; }

  const unsigned char* Ab = A + bz * sA + (long long)(bm * 128) * lda;
  const unsigned char* Bb = B + bz * sB + (long long)(bn * 128) * ldb;

  const int srow = t >> 3;                       // 0..31
  const int gsw = ((t & 7) ^ (srow & 7)) * 16;   // pre-swizzled source granule

  int offA8[4][2], offB8[4][2];
  #pragma unroll
  for (int m = 0; m < 4; ++m)
    #pragma unroll
    for (int h = 0; h < 2; ++h) {
      const int r = wr * 64 + m * 16 + fr;
      offA8[m][h] = r * 128 + (((2 * fq + h) ^ (r & 7)) * 16);
    }
  #pragma unroll
  for (int n = 0; n < 4; ++n)
    #pragma unroll
    for (int h = 0; h < 2; ++h) {
      const int r = wc * 64 + n * 16 + fr;
      offB8[n][h] = r * 128 + (((2 * fq + h) ^ (r & 7)) * 16);
    }

  for (int k0 = 0; k0 < kEnd; k0 += 128) {
    #pragma unroll
    for (int p = 0; p < 4; ++p) {
      gl_lds16(Ab + (long long)(p * 32 + srow) * lda + k0 + gsw, &As8[p * 4096 + t * 16]);
      gl_lds16(Bb + (long long)(p * 32 + srow) * ldb + k0 + gsw, &Bs8[p * 4096 + t * 16]);
    }
    __syncthreads();

    i32x8 af8[4], bv8[4];
    #pragma unroll
    for (int m = 0; m < 4; ++m)
      af8[m] = join8(*(const i32x4*)&As8[offA8[m][0]], *(const i32x4*)&As8[offA8[m][1]]);
    #pragma unroll
    for (int n = 0; n < 4; ++n)
      bv8[n] = join8(*(const i32x4*)&Bs8[offB8[n][0]], *(const i32x4*)&Bs8[offB8[n][1]]);
    #pragma unroll
    for (int m = 0; m < 4; ++m)
      #pragma unroll
      for (int n = 0; n < 4; ++n)
        acc[m][n] = __builtin_amdgcn_mfma_scale_f32_16x16x128_f8f6f4(
            af8[m], bv8[n], acc[m][n], 0, 0, 0, SC127, 0, SC127);
    __syncthreads();
  }

  const int row0 = bm * 128 + wr * 64 + fq * 4;
  const int col0 = bn * 128 + wc * 64 + fr;
  #pragma unroll
  for (int m = 0; m < 4; m++)
    #pragma unroll
    for (int n = 0; n < 4; n++) {
      const int col = col0 + n * 16;
      #pragma unroll
      for (int r = 0; r < 4; r++) {
        const int row = row0 + m * 16 + r;
        const float v = acc[m][n][r] * rescale;
        if (OMODE == 0)
          ((unsigned char*)Cv)[bz * sC + (long long)row * ldc + col] = to_fp8(v);
        else
          ((bf16_t*)Cv)[bz * sC + (long long)row * ldc + col] = (bf16_t)v;
      }
    }
}

// ---------------- shared phase-sync macros (256² 8-phase) ----------------
#define PHASE_MID() do {                                                  \
    asm volatile("" ::: "memory");                                        \
    __builtin_amdgcn_s_barrier();                                         \
    asm volatile("s_waitcnt lgkmcnt(0)" ::: "memory");                    \
    __builtin_amdgcn_sched_barrier(0);                                    \
    __builtin_amdgcn_s_setprio(1);                                        \
  } while (0)

#define PHASE_END() do {                                                  \
    __builtin_amdgcn_s_setprio(0);                                        \
    asm volatile("" ::: "memory");                                        \
    __builtin_amdgcn_s_barrier();                                         \
  } while (0)

// ---------------- 256x256 8-phase MX-fp8 BT-GEMM (QKV / logits) ----------------
// OMODE 0: fp8 out (v*rescale); OMODE 2: f32 out + bias, plain scatter stores
// (R9 evidence: LDS-restaged epilogue is pure overhead; R3/R4: NT stores
// amplify WRITE_SIZE +38%. Plain per-lane stores are optimal here.)
#define STAGE8(buf, h, src, ld, k0) do {                                  \
    gl_lds16((src) + (k0), &lds8[buf][h][tt * 16]);                       \
    gl_lds16((src) + (long long)64 * (ld) + (k0), &lds8[buf][h][8192 + tt * 16]); \
  } while (0)

#define LDA_FRAGS8(buf, qm)                                               \
  _Pragma("unroll") for (int m_ = 0; m_ < 4; ++m_) {                      \
    i32x4 lo_ = *(const i32x4*)&lds8[buf][qm][offA8[m_][0]];              \
    i32x4 hi_ = *(const i32x4*)&lds8[buf][qm][offA8[m_][1]];              \
    af8[m_] = join8(lo_, hi_);                                            \
  }

#define LDB_FRAGS8(buf, qn)                                               \
  _Pragma("unroll") for (int n_ = 0; n_ < 2; ++n_) {                      \
    i32x4 lo_ = *(const i32x4*)&lds8[buf][2 + (qn)][offB8[n_][0]];        \
    i32x4 hi_ = *(const i32x4*)&lds8[buf][2 + (qn)][offB8[n_][1]];        \
    bv8[qn][n_] = join8(lo_, hi_);                                        \
  }

#define MFMA_Q8(qm, qn)                                                   \
  _Pragma("unroll") for (int m_ = 0; m_ < 4; ++m_)                        \
  _Pragma("unroll") for (int n_ = 0; n_ < 2; ++n_)                        \
    acc[qm][qn][m_][n_] = __builtin_amdgcn_mfma_scale_f32_16x16x128_f8f6f4( \
        af8[m_], bv8[qn][n_], acc[qm][qn][m_][n_], 0, 0, 0, SC127, 0, SC127);

template<int OMODE>
__global__ __launch_bounds__(512, 2)
void gemm256_fp8(const unsigned char* __restrict__ A, const unsigned char* __restrict__ B,
                 void* __restrict__ Cv, const float* __restrict__ bias,
                 int K, int lda, int ldb, int ldc, int nbn, float rescale) {
  __shared__ unsigned char lds8[2][4][16384];

  const int nwg = gridDim.x;
  const int bid = blockIdx.x;
  const int swz = (nwg & 7) ? bid : ((bid & 7) * (nwg >> 3) + (bid >> 3));
  const int per_group = 8 * nbn;
  const int g   = swz / per_group;
  const int rem = swz - g * per_group;
  const int bm = g * 8 + (rem & 7);
  const int bn = rem >> 3;

  const int tt = threadIdx.x;
  const int lane = tt & 63;
  const int w = tt >> 6;
  const int wr = w >> 2, wc = w & 3;
  const int fr = lane & 15, fq = lane >> 4;

  const int srow = tt >> 3;
  const int gl = (tt & 7) ^ (srow & 7);
  const unsigned char* sA0 = A + (long long)(bm * 256 +       srow) * lda + gl * 16;
  const unsigned char* sA1 = A + (long long)(bm * 256 + 128 + srow) * lda + gl * 16;
  const unsigned char* sB0 = B + (long long)(bn * 256 +       srow) * ldb + gl * 16;
  const unsigned char* sB1 = B + (long long)(bn * 256 + 128 + srow) * ldb + gl * 16;

  int offA8[4][2], offB8[2][2];
  #pragma unroll
  for (int m = 0; m < 4; ++m)
    #pragma unroll
    for (int h = 0; h < 2; ++h) {
      const int r = wr * 64 + m * 16 + fr;
      offA8[m][h] = r * 128 + (((2 * fq + h) ^ (r & 7)) * 16);
    }
  #pragma unroll
  for (int n = 0; n < 2; ++n)
    #pragma unroll
    for (int h = 0; h < 2; ++h) {
      const int r = wc * 32 + n * 16 + fr;
      offB8[n][h] = r * 128 + (((2 * fq + h) ^ (r & 7)) * 16);
    }

  f32x4 acc[2][2][4][2];
  #pragma unroll
  for (int i = 0; i < 2; ++i)
    #pragma unroll
    for (int j = 0; j < 2; ++j)
      #pragma unroll
      for (int m = 0; m < 4; ++m)
        #pragma unroll
        for (int n = 0; n < 2; ++n)
          #pragma unroll
          for (int r = 0; r < 4; ++r) acc[i][j][m][n][r] = 0.f;

  i32x8 af8[4], bv8[2][2];
  const int NT = K >> 7;

  STAGE8(0, 0, sA0, lda, 0); STAGE8(0, 1, sA1, lda, 0);
  STAGE8(0, 2, sB0, ldb, 0); STAGE8(0, 3, sB1, ldb, 0);
  STAGE8(1, 0, sA0, lda, 128); STAGE8(1, 3, sB1, ldb, 128); STAGE8(1, 1, sA1, lda, 128);
  asm volatile("s_waitcnt vmcnt(6)" ::: "memory");
  __builtin_amdgcn_s_barrier();

  int b = 0;
  for (int t = 0; t < NT; ++t, b ^= 1) {
    const int nb = b ^ 1;
    const long long k1 = (long long)(t + 1) << 7;
    const long long k2 = (long long)(t + 2) << 7;

    LDA_FRAGS8(b, 0)
    LDB_FRAGS8(b, 0)
    if (t + 1 < NT) STAGE8(nb, 2, sB0, ldb, k1);
    PHASE_MID();
    MFMA_Q8(0, 0)
    PHASE_END();

    LDB_FRAGS8(b, 1)
    if (t + 2 < NT) STAGE8(b, 0, sA0, lda, k2);
    PHASE_MID();
    MFMA_Q8(0, 1)
    PHASE_END();

    LDA_FRAGS8(b, 1)
    if (t + 2 < NT) STAGE8(b, 3, sB1, ldb, k2);
    PHASE_MID();
    MFMA_Q8(1, 1)
    PHASE_END();

    if (t + 2 < NT) STAGE8(b, 1, sA1, lda, k2);
    PHASE_MID();
    MFMA_Q8(1, 0)
    __builtin_amdgcn_s_setprio(0);
    if (t < NT - 1) {
      if (t <= NT - 3) asm volatile("s_waitcnt vmcnt(6)" ::: "memory");
      else             asm volatile("s_waitcnt vmcnt(0)" ::: "memory");
    }
    asm volatile("" ::: "memory");
    __builtin_amdgcn_s_barrier();
  }

  #pragma unroll
  for (int qm = 0; qm < 2; ++qm)
    #pragma unroll
    for (int qn = 0; qn < 2; ++qn)
      #pragma unroll
      for (int m = 0; m < 4; ++m)
        #pragma unroll
        for (int n = 0; n < 2; ++n) {
          const int row0 = bm * 256 + qm * 128 + wr * 64 + m * 16 + fq * 4;
          const int col  = bn * 256 + qn * 128 + wc * 32 + n * 16 + fr;
          const float bb = (OMODE == 2) ? bias[col] : 0.f;
          #pragma unroll
          for (int r = 0; r < 4; ++r) {
            const float v = acc[qm][qn][m][n][r] * rescale + bb;
            if (OMODE == 0)
              ((unsigned char*)Cv)[(long long)(row0 + r) * ldc + col] = to_fp8(v);
            else
              ((float*)Cv)[(long long)(row0 + r) * ldc + col] = v;
          }
        }
}

// ---------------- row softmax (bf16 scores in, A-f32 + A-fp8x256 out) ----------------
__device__ __forceinline__ float wred_max(float v) {
  #pragma unroll
  for (int o = 32; o; o >>= 1) v = fmaxf(v, __shfl_xor(v, o, 64));
  return v;
}
__device__ __forceinline__ float wred_sum(float v) {
  #pragma unroll
  for (int o = 32; o; o >>= 1) v += __shfl_xor(v, o, 64);
  return v;
}

__global__ __launch_bounds__(256)
void softmax_rows(bf16_t* Abf, float* __restrict__ Aout) {
  const int m = blockIdx.x;          // 0..8191
  const int q = m & (SEQ - 1);
  const int t = threadIdx.x;
  const int base = t * 8;
  bf16_t* srow = Abf + (long long)m * SEQ;

  bf16x8 sv = *(const bf16x8*)(srow + base);
  float v[8];
  float mx = -INFINITY;
  #pragma unroll
  for (int i = 0; i < 8; i++) {
    v[i] = (base + i <= q) ? (float)sv[i] : -INFINITY;
    mx = fmaxf(mx, v[i]);
  }
  __shared__ float redm[4], reds[4];
  const int lane = t & 63, w = t >> 6;
  float wm = wred_max(mx);
  if (lane == 0) redm[w] = wm;
  __syncthreads();
  mx = fmaxf(fmaxf(redm[0], redm[1]), fmaxf(redm[2], redm[3]));

  float e[8]; float s = 0.f;
  #pragma unroll
  for (int i = 0; i < 8; i++) {
    e[i] = (base + i <= q) ? __expf(v[i] - mx) : 0.f;
    s += e[i];
  }
  float wsu = wred_sum(s);
  if (lane == 0) reds[w] = wsu;
  __syncthreads();                 // all loads complete before any store below
  s = reds[0] + reds[1] + reds[2] + reds[3];
  const float inv = 1.f / s;

  f32x4 o0, o1;
  float av[8];
  #pragma unroll
  for (int i = 0; i < 8; i++) av[i] = e[i] * inv;
  o0[0] = av[0]; o0[1] = av[1]; o0[2] = av[2]; o0[3] = av[3];
  o1[0] = av[4]; o1[1] = av[5]; o1[2] = av[6]; o1[3] = av[7];
  float* orow = Aout + (long long)m * SEQ;
  __builtin_nontemporal_store(o0, (f32x4*)(orow) + t * 2);
  __builtin_nontemporal_store(o1, (f32x4*)(orow) + t * 2 + 1);

  // A8 = fp8(A*256), in place over the scores row
  int lo = 0, hi = 0;
  lo = __builtin_amdgcn_cvt_pk_fp8_f32(av[0] * 256.f, av[1] * 256.f, lo, false);
  lo = __builtin_amdgcn_cvt_pk_fp8_f32(av[2] * 256.f, av[3] * 256.f, lo, true);
  hi = __builtin_amdgcn_cvt_pk_fp8_f32(av[4] * 256.f, av[5] * 256.f, hi, false);
  hi = __builtin_amdgcn_cvt_pk_fp8_f32(av[6] * 256.f, av[7] * 256.f, hi, true);
  *(int2*)((unsigned char*)srow + base) = make_int2(lo, hi);
}

// ---------------- launch ----------------
extern "C" void kernel_launch(void* const* d_in, const int* in_sizes, int n_in,
                              void* d_out, int out_size, void* d_ws, size_t ws_size,
                              hipStream_t stream) {
  const int*   idx   = (const int*)d_in[0];
  const float* embed = (const float*)d_in[1];
  const float* Wq    = (const float*)d_in[2];
  const float* Wk    = (const float*)d_in[3];
  const float* Wv    = (const float*)d_in[4];
  const float* Wout  = (const float*)d_in[5];
  const float* bout  = (const float*)d_in[6];

  float* out = (float*)d_out;
  char*  ws  = (char*)d_ws;

  unsigned char* Wqkv8 = (unsigned char*)(ws + WQKV_OFF);
  unsigned char* Wout8 = (unsigned char*)(ws + WOUT_OFF);
  unsigned char* Ao8   = (unsigned char*)(ws + AO8_OFF);
  unsigned char* X8    = (unsigned char*)(ws + X8_OFF);
  unsigned char* QKV8  = (unsigned char*)(ws + QKV8_OFF);
  unsigned char* Vt8   = (unsigned char*)(ws + VT_OFF);
  bf16_t*        Abf   = (bf16_t*)(ws + ABF_OFF);   // scores bf16; A8 fp8 in place
  float*         Aout  = out + LOGITS_ELEMS;

  // weight quants (x64 for QKV weights, x32 for Wout)
  quant_fp8_qkv<<<1536, 256, 0, stream>>>(Wq, Wk, Wv, (int2*)Wqkv8);
  quant_fp8_f32<<<2048, 256, 0, stream>>>(Wout, (int2*)Wout8, 4096000, 32.f);

  // x8 = fp8(embed[idx] * 64)
  gather_fp8<<<8192, 256, 0, stream>>>(idx, embed, X8);

  // QKV8 = fp8((X8 @ Wqkv8^T)/64)   (256² 8-phase fp8, 32bm x 12bn)
  gemm256_fp8<0><<<dim3(384), 512, 0, stream>>>(
      X8, Wqkv8, QKV8, nullptr, 1024, 1024, 1024, 3072, 12, 1.f / 64.f);

  // Vt8[b][d][s]
  transpose_v8<<<dim3(32, 16, 4), 256, 0, stream>>>(QKV8, Vt8);

  // scores bf16 = (Q.K^T) * 2^-17, causal tiles only
  gemm_bt_fp8<3, true, false><<<dim3(16, 16, 4), 256, 0, stream>>>(
      QKV8, QKV8 + 1024, Abf, 1024, 3072, 3072, 2048,
      2048LL * 3072, 2048LL * 3072, 2048LL * 2048, 1.f / 131072.f);

  // softmax: A f32 -> d_out, A8 = fp8(A*256) in place
  softmax_rows<<<8192, 256, 0, stream>>>(Abf, Aout);

  // Ao8 = fp8(attn_out * 256) = fp8(acc/64)   (K trimmed to causal extent)
  gemm_bt_fp8<0, false, true><<<dim3(8, 16, 4), 256, 0, stream>>>(
      (unsigned char*)Abf, Vt8, Ao8, 2048, 4096, 2048, 1024,
      2048LL * 4096, 1024LL * 2048, 2048LL * 1024, 1.f / 64.f);

  // logits = attn_out @ Wout^T + bout  (MX-fp8 256² 8-phase, 32bm x 125bn)
  gemm256_fp8<2><<<dim3(4000), 512, 0, stream>>>(
      Ao8, Wout8, out, bout, 1024, 1024, 1024, VOCAB, 125, 1.f / 8192.f);
}